// Round 9
// baseline (101.648 us; speedup 1.0000x reference)
//
#include <hip/hip_runtime.h>
#include <math.h>

#define NB 8192
#define NF 512
#define NP 64
#define NC 100
#define NR 16
#define EPSF 1e-4f
#define LOG2E  1.44269504088896340736f

using short8  = __attribute__((ext_vector_type(8))) short;
using floatx4 = __attribute__((ext_vector_type(4))) float;

// pack 2 f32 -> 2 bf16 (truncation) in one dword; 8 f32 -> short8 frag
__device__ __forceinline__ unsigned pk2(float a, float b) {
  return (__float_as_uint(b) & 0xffff0000u) | (__float_as_uint(a) >> 16);
}
__device__ __forceinline__ short8 pk8(float4 a, float4 b) {
  union { uint4 u; short8 s; } cv;
  cv.u.x = pk2(a.x, a.y); cv.u.y = pk2(a.z, a.w);
  cv.u.z = pk2(b.x, b.y); cv.u.w = pk2(b.z, b.w);
  return cv.s;
}

// ---- LDS layout (bytes) ----
#define OFF_U     0        // u[64][128] f32 = 32768
#define OFF_SI    32768    // si[16][64]      = 4096
#define OFF_PK4   36864    // pk4[8][64] f4   = 8192
#define OFF_REDB  45056    // 256 f32
#define OFF_RMAX  46080    // 64 f32
#define OFF_UMAX  46336    // 64 f32
#define OFF_OMF   46592    // 8 f32
#define SMEM_SZ   46624

// One fused kernel, 512 blocks (2/CU) x 256 threads, 16 rows/block.
// GEMM: NO LDS STAGING — MFMA A/B fragments (A[m=lane&15][k=qd*8+j],
//   B[n=lane&15][k=qd*8+j]) are 8 contiguous row-major elements, loaded
//   directly from global (x row R0+ml, w row 16wv+ml; x 4x wave redundancy
//   is L1/L2-absorbed, w is L2-hot) and packed to bf16 in-reg. xsq/wsq
//   fold into the same pass; si is wave-local. Only 2 block barriers total.
// Scan (R7-measured-best): half-wave per row, 4 classes/lane, suffix-product
//   form; pk4/omf are half-wave-private so the scan needs NO barriers
//   (wave-internal lgkmcnt ordering suffices — R7's B4/B5 were superfluous).
// All reductions butterflies/fixed-order => bitwise deterministic.
__global__ __launch_bounds__(256, 2)
void ds_one(const float* __restrict__ x, const float* __restrict__ w,
            const float* __restrict__ xi, const float* __restrict__ eta,
            const float* __restrict__ beta, float* __restrict__ out)
{
  __shared__ __align__(16) char smem[SMEM_SZ];
  float*  u_l  = (float*)(smem + OFF_U);
  float*  si_l = (float*)(smem + OFF_SI);
  float4* pk4  = (float4*)(smem + OFF_PK4);
  float*  redb = (float*)(smem + OFF_REDB);
  float*  rmax = (float*)(smem + OFF_RMAX);
  float*  umax = (float*)(smem + OFF_UMAX);
  float*  omf  = (float*)(smem + OFF_OMF);

  const int t    = threadIdx.x;
  const int R0   = blockIdx.x * NR;
  const int wv   = t >> 6;
  const int l6   = t & 63;
  const int ml   = l6 & 15;               // MFMA m/n lane
  const int qd   = l6 >> 4;               // MFMA quad
  const int pcol = wv * 16 + ml;          // this lane's p (w row)

  // ---- GEMM + squares: direct-from-global fragments, full K unrolled ----
  const float* xp = x + (size_t)(R0 + ml) * NF + qd * 8;
  const float* wp = w + (size_t)pcol      * NF + qd * 8;
  float xsq = 0.f, wsq = 0.f;
  floatx4 acc = {0.f, 0.f, 0.f, 0.f};
  #pragma unroll
  for (int ks = 0; ks < 16; ++ks) {
    float4 xa = *(const float4*)&xp[ks * 32];
    float4 xb = *(const float4*)&xp[ks * 32 + 4];
    float4 wa = *(const float4*)&wp[ks * 32];
    float4 wb = *(const float4*)&wp[ks * 32 + 4];
    xsq += xa.x*xa.x + xa.y*xa.y + xa.z*xa.z + xa.w*xa.w
         + xb.x*xb.x + xb.y*xb.y + xb.z*xb.z + xb.w*xb.w;
    wsq += wa.x*wa.x + wa.y*wa.y + wa.z*wa.z + wa.w*wa.w
         + wb.x*wb.x + wb.y*wb.y + wb.z*wb.z + wb.w*wb.w;
    acc = __builtin_amdgcn_mfma_f32_16x16x32_bf16(pk8(xa, xb), pk8(wa, wb),
                                                  acc, 0, 0, 0);
  }
  // combine the 4 qd-slices (xor 16,32): per-lane deterministic
  xsq += __shfl_xor(xsq, 16, 64); xsq += __shfl_xor(xsq, 32, 64);
  wsq += __shfl_xor(wsq, 16, 64); wsq += __shfl_xor(wsq, 32, 64);

  // ---- si (wave-local) + row-max partials + beta partials ----
  float si4[4];
  {
    float e  = eta[pcol];
    float kg = -LOG2E * e * e;            // exp(-g*d) = exp2(kg*d)
    float al = 1.f / (1.f + __expf(-xi[pcol]));
    #pragma unroll
    for (int i = 0; i < 4; ++i) {
      float xsr = __shfl(xsq, qd * 4 + i, 64);   // bpermute, per-lane index
      float d = xsr + wsq - 2.f * acc[i];
      si4[i] = al * exp2f(kg * d);
    }
    #pragma unroll
    for (int i = 0; i < 4; ++i) {
      float m = si4[i];
      m = fmaxf(m, __shfl_xor(m, 1, 64)); m = fmaxf(m, __shfl_xor(m, 2, 64));
      m = fmaxf(m, __shfl_xor(m, 4, 64)); m = fmaxf(m, __shfl_xor(m, 8, 64));
      if (ml == 0) rmax[(qd * 4 + i) * 4 + wv] = m;
    }
  }
  const int p4 = t >> 2, q4 = t & 3;
  {
    const float* br = beta + p4 * NC + q4 * 25;
    float s = 0.f;
    #pragma unroll 5
    for (int j = 0; j < 25; ++j) { float b = br[j]; s = fmaf(b, b, s); }
    redb[q4 * 64 + p4] = s;
  }
  __syncthreads();                        // B1

  // ---- si finalize -> si_l; u fill + umax ----
  #pragma unroll
  for (int i = 0; i < 4; ++i) {
    const int row = qd * 4 + i;
    float m = fmaxf(fmaxf(rmax[row * 4 + 0], rmax[row * 4 + 1]),
                    fmaxf(rmax[row * 4 + 2], rmax[row * 4 + 3]));
    si_l[row * 64 + pcol] = si4[i] * (1.f / (m + EPSF));
  }
  {
    const float bi = 1.f / (((redb[p4] + redb[64 + p4]) + redb[128 + p4]) + redb[192 + p4]);
    float um = 0.f;
    #pragma unroll
    for (int i2 = 0; i2 < 8; ++i2) {
      const int q = q4 + 4 * i2;          // col quad 0..31 (NC=100 = quads 0..24)
      float4 uv = make_float4(0.f, 0.f, 0.f, 0.f);
      if (q < 25) {
        const float* br = beta + p4 * NC + q * 4;
        uv.x = br[0]*br[0]*bi; uv.y = br[1]*br[1]*bi;
        uv.z = br[2]*br[2]*bi; uv.w = br[3]*br[3]*bi;
      }
      um = fmaxf(um, fmaxf(fmaxf(uv.x, uv.y), fmaxf(uv.z, uv.w)));
      *(float4*)&u_l[p4 * 128 + q * 4] = uv;
    }
    um = fmaxf(um, __shfl_xor(um, 1, 64));
    um = fmaxf(um, __shfl_xor(um, 2, 64));
    if (q4 == 0) umax[p4] = um;
  }
  __syncthreads();                        // B2 (last barrier)

  // ---- scan: half-wave per row, 4 classes/lane, 2 passes (R7-proven) ----
  const int lane = t & 31;
  const int row8 = t >> 5;
  #pragma unroll 1
  for (int pass = 0; pass < 2; ++pass) {
    const int srow = pass * 8 + row8;
    {   // scaled factors (st,ot) and weights W via Kogge-Stone on 3*ot
      float sp0 = si_l[srow * 64 + lane];
      float sp1 = si_l[srow * 64 + 32 + lane];
      float um0 = umax[lane], um1 = umax[32 + lane];
      float om0 = 1.f - sp0, om1 = 1.f - sp1;
      float c0 = 1.f / fmaf(sp0, um0, om0);   // scale: max_c(vt) ~ 1 -> T <= 1
      float c1 = 1.f / fmaf(sp1, um1, om1);
      float st0 = sp0 * c0, ot0 = om0 * c0;
      float st1 = sp1 * c1, ot1 = om1 * c1;
      float pA = 3.f * ot0, pB = 3.f * ot1;   // prefix of (3*omt) folds 3^k in
      #pragma unroll
      for (int d2 = 1; d2 < 32; d2 <<= 1) {
        float uA = __shfl_up(pA, d2, 32);
        float uB = __shfl_up(pB, d2, 32);
        if (lane >= d2) { pA *= uA; pB *= uB; }
      }
      float totA = __shfl(pA, 31, 32);
      float w0 = (lane == 0) ? 0.f : pA * (1.f / 9.f);   // 3^(k-1) prod omt
      float w1 = (totA * pB) * (1.f / 9.f);
      pk4[row8 * 64 + lane]      = make_float4(st0, ot0, w0, 0.f);
      pk4[row8 * 64 + 32 + lane] = make_float4(st1, ot1, w1, 0.f);
      if (lane == 31) omf[row8] = (totA * pB) * (1.f / 3.f);  // 3^63 prod omt
    }
    // wave-private pk4/omf: lgkmcnt ordering suffices, no barrier
    float4 T = make_float4(1.f, 1.f, 1.f, 1.f);
    float4 S = make_float4(0.f, 0.f, 0.f, 0.f);
    for (int p = 63; p >= 0; --p) {       // S += W_p*T BEFORE T *= vt_p
      float4 f  = pk4[row8 * 64 + p];     // (st, ot, W) broadcast
      float4 uv = *(const float4*)&u_l[p * 128 + lane * 4];
      S.x = fmaf(f.z, T.x, S.x); S.y = fmaf(f.z, T.y, S.y);
      S.z = fmaf(f.z, T.z, S.z); S.w = fmaf(f.z, T.w, S.w);
      T.x *= fmaf(f.x, uv.x, f.y);
      T.y *= fmaf(f.x, uv.y, f.y);
      T.z *= fmaf(f.x, uv.z, f.y);
      T.w *= fmaf(f.x, uv.w, f.y);
    }
    float om = omf[row8];
    float m0 = fmaf(2.f, S.x, T.x) - om;
    float m1 = fmaf(2.f, S.y, T.y) - om;
    float m2 = fmaf(2.f, S.z, T.z) - om;
    float m3 = fmaf(2.f, S.w, T.w) - om;
    if (lane >= 25) { m0 = 0.f; m1 = 0.f; m2 = 0.f; m3 = 0.f; }
    float ss = (m0 + m1) + (m2 + m3);
    #pragma unroll
    for (int msk = 1; msk < 32; msk <<= 1) ss += __shfl_xor(ss, msk, 32);
    float rn = 1.f / (ss + om);
    float* orow = &out[(size_t)(R0 + srow) * 101];
    if (lane < 25) {
      orow[lane * 4 + 0] = m0 * rn; orow[lane * 4 + 1] = m1 * rn;
      orow[lane * 4 + 2] = m2 * rn; orow[lane * 4 + 3] = m3 * rn;
    } else if (lane == 25) {
      orow[100] = om * rn;
    }
  }
}

extern "C" void kernel_launch(void* const* d_in, const int* in_sizes, int n_in,
                              void* d_out, int out_size, void* d_ws, size_t ws_size,
                              hipStream_t stream)
{
  const float* x    = (const float*)d_in[0];
  const float* w    = (const float*)d_in[1];
  const float* xi   = (const float*)d_in[2];
  const float* eta  = (const float*)d_in[3];
  const float* beta = (const float*)d_in[4];
  (void)d_ws; (void)ws_size;
  hipLaunchKernelGGL(ds_one, dim3(NB / NR), dim3(256), 0, stream,
                     x, w, xi, eta, beta, (float*)d_out);
}

// Round 10
// 84.544 us; speedup vs baseline: 1.2023x; 1.2023x over previous
//
#include <hip/hip_runtime.h>
#include <math.h>

#define NB 8192
#define NF 512
#define NP 64
#define NC 100
#define NR 16
#define EPSF 1e-4f
#define LOG2E  1.44269504088896340736f

using short8  = __attribute__((ext_vector_type(8))) short;
using floatx4 = __attribute__((ext_vector_type(4))) float;

// pack 2 f32 -> bf16 pair in one dword (truncation); validated R6-R9
__device__ __forceinline__ unsigned pk2(float a, float b) {
  return (__float_as_uint(b) & 0xffff0000u) | (__float_as_uint(a) >> 16);
}
__device__ __forceinline__ uint2 pkbf(float4 v) {
  uint2 r; r.x = pk2(v.x, v.y); r.y = pk2(v.z, v.w); return r;
}

// ---- LDS layout (bytes) ----
// staging xh[16][136]s / wh[64][136]s  [0,21760) unions u_l bf16[64][128] [0,16384)
#define OFF_XH    0
#define OFF_WH    4352
#define OFF_U     0
#define OFF_SI    21760
#define OFF_PK4   25856
#define OFF_REDB  34048
#define OFF_RMAX  35072
#define OFF_UMAX  35328
#define OFF_XSQL  35584
#define OFF_WSQL  35648
#define OFF_KGAM  35904
#define OFF_ALPH  36160
#define OFF_OMF   36416
#define SMEM_SZ   36448

// One fused kernel, 512 blocks (2/CU) x 256 threads, 16 rows/block.
// GEMM (R8-validated): bf16 MFMA 16x16x32, BK=128 (4 chunks), register
//   prefetch of next chunk's global loads, staging stride 136 shorts
//   (odd bank-quad count -> conflict-free b128 frag reads). 8 barriers.
// Scan (R7-validated, barriers removed per R9 validation): half-wave per
//   row, 4 classes/lane, suffix-product form:
//   v' = v1 v2 + 2 om1 om2, om' = 3 om1 om2  (per-step normalizer = pure
//   scale, cancels in final normalize):
//   v_fin[c] = prod_p vt_p[c] + 2 sum_k W_k T_k[c],  T_k = prod_{j>k} vt_j,
//   W_k = 3^(k-1) prod_{j<=k} omt_j (3^k folded into Kogge-Stone of 3*omt),
//   om_fin = 3^63 prod omt.  pk4/omf are half-wave-private -> no barriers.
// u stored bf16 (scan u read b128->b64; out is omega-dominated, bf16-u
//   perturbs masses ~0.2% rel on ~1e-6 values -> absmax ~1e-5 vs 2e-2).
// All reductions butterflies/fixed-order => bitwise deterministic.
__global__ __launch_bounds__(256, 2)
void ds_one(const float* __restrict__ x, const float* __restrict__ w,
            const float* __restrict__ xi, const float* __restrict__ eta,
            const float* __restrict__ beta, float* __restrict__ out)
{
  __shared__ __align__(16) char smem[SMEM_SZ];
  short*          xh    = (short*)(smem + OFF_XH);
  short*          wh    = (short*)(smem + OFF_WH);
  unsigned short* u_l   = (unsigned short*)(smem + OFF_U);
  float*          si_l  = (float*)(smem + OFF_SI);
  float4*         pk4   = (float4*)(smem + OFF_PK4);
  float*          redb  = (float*)(smem + OFF_REDB);
  float*          rmax  = (float*)(smem + OFF_RMAX);
  float*          umaxl = (float*)(smem + OFF_UMAX);
  float*          xsql  = (float*)(smem + OFF_XSQL);
  float*          wsql  = (float*)(smem + OFF_WSQL);
  float*          kgaml = (float*)(smem + OFF_KGAM);
  float*          alphl = (float*)(smem + OFF_ALPH);
  float*          omf   = (float*)(smem + OFF_OMF);

  const int t    = threadIdx.x;
  const int R0   = blockIdx.x * NR;
  const int wv   = t >> 6;
  const int wl   = t & 63;
  const int ml   = wl & 15;               // MFMA m/n lane
  const int qd   = wl >> 4;               // MFMA quad
  const int pcol = wv * 16 + ml;
  const int xrow = t >> 4, xq = t & 15;   // staging roles

  // ---- GEMM: D = x . w^T, BK=128, 4 chunks, register prefetch ----
  float xsq_acc = 0.f;
  float wacc[4] = {0.f, 0.f, 0.f, 0.f};
  floatx4 acc = {0.f, 0.f, 0.f, 0.f};
  float4 xr0, xr1, wr[4][2];

  {   // prefetch chunk 0
    const float* xp = &x[(size_t)(R0 + xrow) * NF + xq * 8];
    xr0 = *(const float4*)&xp[0];  xr1 = *(const float4*)&xp[4];
    #pragma unroll
    for (int g = 0; g < 4; ++g) {
      const int row = wv * 16 + g * 4 + (wl >> 4);
      const float* wp = &w[(size_t)row * NF + xq * 8];
      wr[g][0] = *(const float4*)&wp[0];  wr[g][1] = *(const float4*)&wp[4];
    }
  }
  for (int ch = 0; ch < 4; ++ch) {
    __syncthreads();                      // prev chunk's frags consumed
    {
      xsq_acc += xr0.x*xr0.x + xr0.y*xr0.y + xr0.z*xr0.z + xr0.w*xr0.w
               + xr1.x*xr1.x + xr1.y*xr1.y + xr1.z*xr1.z + xr1.w*xr1.w;
      *(uint2*)&xh[xrow * 136 + xq * 8]     = pkbf(xr0);
      *(uint2*)&xh[xrow * 136 + xq * 8 + 4] = pkbf(xr1);
    }
    #pragma unroll
    for (int g = 0; g < 4; ++g) {
      const int row = wv * 16 + g * 4 + (wl >> 4);
      float4 a = wr[g][0], b = wr[g][1];
      wacc[g] += a.x*a.x + a.y*a.y + a.z*a.z + a.w*a.w
               + b.x*b.x + b.y*b.y + b.z*b.z + b.w*b.w;
      *(uint2*)&wh[row * 136 + xq * 8]     = pkbf(a);
      *(uint2*)&wh[row * 136 + xq * 8 + 4] = pkbf(b);
    }
    __syncthreads();
    if (ch < 3) {                         // prefetch next chunk (overlaps MFMA)
      const int kb = (ch + 1) * 128;
      const float* xp = &x[(size_t)(R0 + xrow) * NF + kb + xq * 8];
      xr0 = *(const float4*)&xp[0];  xr1 = *(const float4*)&xp[4];
      #pragma unroll
      for (int g = 0; g < 4; ++g) {
        const int row = wv * 16 + g * 4 + (wl >> 4);
        const float* wp = &w[(size_t)row * NF + kb + xq * 8];
        wr[g][0] = *(const float4*)&wp[0];  wr[g][1] = *(const float4*)&wp[4];
      }
    }
    #pragma unroll
    for (int ks = 0; ks < 4; ++ks) {
      short8 a = *(const short8*)&xh[ml * 136 + ks * 32 + qd * 8];
      short8 b = *(const short8*)&wh[(wv * 16 + ml) * 136 + ks * 32 + qd * 8];
      acc = __builtin_amdgcn_mfma_f32_16x16x32_bf16(a, b, acc, 0, 0, 0);
    }
  }

  // ---- P1: beta partials; xsq/wsq butterflies; kgam/alpha ----
  const int p4 = t >> 2, q4 = t & 3;
  {
    const float* br = beta + p4 * NC + q4 * 25;
    float s = 0.f;
    #pragma unroll 5
    for (int j = 0; j < 25; ++j) { float b = br[j]; s = fmaf(b, b, s); }
    redb[q4 * 64 + p4] = s;
  }
  {
    float s = xsq_acc;
    s += __shfl_xor(s, 1, 64); s += __shfl_xor(s, 2, 64);
    s += __shfl_xor(s, 4, 64); s += __shfl_xor(s, 8, 64);
    if (xq == 0) xsql[xrow] = s;
  }
  #pragma unroll
  for (int g = 0; g < 4; ++g) {
    float s = wacc[g];
    s += __shfl_xor(s, 1, 64); s += __shfl_xor(s, 2, 64);
    s += __shfl_xor(s, 4, 64); s += __shfl_xor(s, 8, 64);
    if (xq == 0) wsql[wv * 16 + g * 4 + (wl >> 4)] = s;
  }
  if (t < 64) {
    float e = eta[t];
    kgaml[t] = -LOG2E * e * e;            // exp(-g*d) = exp2(kgam*d)
    alphl[t] = 1.f / (1.f + __expf(-xi[t]));
  }
  __syncthreads();                        // B1

  // ---- P2: si in MFMA-C layout + per-row 16-lane max partials ----
  float si4[4];
  {
    const float wq = wsql[pcol], kg = kgaml[pcol], al = alphl[pcol];
    #pragma unroll
    for (int i = 0; i < 4; ++i) {
      float d = xsql[qd * 4 + i] + wq - 2.f * acc[i];
      si4[i] = al * exp2f(kg * d);
    }
    #pragma unroll
    for (int i = 0; i < 4; ++i) {
      float m = si4[i];
      m = fmaxf(m, __shfl_xor(m, 1, 64)); m = fmaxf(m, __shfl_xor(m, 2, 64));
      m = fmaxf(m, __shfl_xor(m, 4, 64)); m = fmaxf(m, __shfl_xor(m, 8, 64));
      if (ml == 0) rmax[(qd * 4 + i) * 4 + wv] = m;
    }
  }
  __syncthreads();                        // B2

  // ---- P3: si finalize -> si_l; u fill (bf16, over dead staging) + umax ----
  #pragma unroll
  for (int i = 0; i < 4; ++i) {
    const int row = qd * 4 + i;
    float m = fmaxf(fmaxf(rmax[row * 4 + 0], rmax[row * 4 + 1]),
                    fmaxf(rmax[row * 4 + 2], rmax[row * 4 + 3]));
    si_l[row * 64 + pcol] = si4[i] * (1.f / (m + EPSF));
  }
  {
    const float bi = 1.f / (((redb[p4] + redb[64 + p4]) + redb[128 + p4]) + redb[192 + p4]);
    float um = 0.f;
    #pragma unroll
    for (int i2 = 0; i2 < 8; ++i2) {
      const int q = q4 + 4 * i2;          // col quad 0..31 (NC=100 = quads 0..24)
      float4 uv = make_float4(0.f, 0.f, 0.f, 0.f);
      if (q < 25) {
        const float* br = beta + p4 * NC + q * 4;
        uv.x = br[0]*br[0]*bi; uv.y = br[1]*br[1]*bi;
        uv.z = br[2]*br[2]*bi; uv.w = br[3]*br[3]*bi;
      }
      um = fmaxf(um, fmaxf(fmaxf(uv.x, uv.y), fmaxf(uv.z, uv.w)));
      *(uint2*)&u_l[p4 * 128 + q * 4] = pkbf(uv);
    }
    um = fmaxf(um, __shfl_xor(um, 1, 64));
    um = fmaxf(um, __shfl_xor(um, 2, 64));
    if (q4 == 0) umaxl[p4] = um;
  }
  __syncthreads();                        // B3 (last barrier)

  // ---- scan: half-wave per row, 4 classes/lane, 2 passes, barrier-free ----
  const int lane = t & 31;
  const int row8 = t >> 5;
  #pragma unroll 1
  for (int pass = 0; pass < 2; ++pass) {
    const int srow = pass * 8 + row8;
    {   // scaled factors (st,ot) and weights W via Kogge-Stone on 3*ot
      float sp0 = si_l[srow * 64 + lane];
      float sp1 = si_l[srow * 64 + 32 + lane];
      float um0 = umaxl[lane], um1 = umaxl[32 + lane];
      float om0 = 1.f - sp0, om1 = 1.f - sp1;
      float c0 = 1.f / fmaf(sp0, um0, om0);   // scale: max_c(vt) ~ 1 -> T <= 1
      float c1 = 1.f / fmaf(sp1, um1, om1);
      float st0 = sp0 * c0, ot0 = om0 * c0;
      float st1 = sp1 * c1, ot1 = om1 * c1;
      float pA = 3.f * ot0, pB = 3.f * ot1;   // prefix of (3*omt) folds 3^k in
      #pragma unroll
      for (int d2 = 1; d2 < 32; d2 <<= 1) {
        float uA = __shfl_up(pA, d2, 32);
        float uB = __shfl_up(pB, d2, 32);
        if (lane >= d2) { pA *= uA; pB *= uB; }
      }
      float totA = __shfl(pA, 31, 32);
      float w0 = (lane == 0) ? 0.f : pA * (1.f / 9.f);   // 3^(k-1) prod omt
      float w1 = (totA * pB) * (1.f / 9.f);
      pk4[row8 * 64 + lane]      = make_float4(st0, ot0, w0, 0.f);
      pk4[row8 * 64 + 32 + lane] = make_float4(st1, ot1, w1, 0.f);
      if (lane == 31) omf[row8] = (totA * pB) * (1.f / 3.f);  // 3^63 prod omt
    }
    // pk4/omf half-wave-private: wave-internal lgkmcnt ordering, no barrier
    float4 T = make_float4(1.f, 1.f, 1.f, 1.f);
    float4 S = make_float4(0.f, 0.f, 0.f, 0.f);
    for (int p = 63; p >= 0; --p) {       // S += W_p*T BEFORE T *= vt_p
      float4 f  = pk4[row8 * 64 + p];     // (st, ot, W) broadcast
      uint2 ud  = *(const uint2*)&u_l[p * 128 + lane * 4];
      float u0 = __uint_as_float(ud.x << 16);
      float u1 = __uint_as_float(ud.x & 0xffff0000u);
      float u2 = __uint_as_float(ud.y << 16);
      float u3 = __uint_as_float(ud.y & 0xffff0000u);
      S.x = fmaf(f.z, T.x, S.x); S.y = fmaf(f.z, T.y, S.y);
      S.z = fmaf(f.z, T.z, S.z); S.w = fmaf(f.z, T.w, S.w);
      T.x *= fmaf(f.x, u0, f.y);
      T.y *= fmaf(f.x, u1, f.y);
      T.z *= fmaf(f.x, u2, f.y);
      T.w *= fmaf(f.x, u3, f.y);
    }
    float om = omf[row8];
    float m0 = fmaf(2.f, S.x, T.x) - om;
    float m1 = fmaf(2.f, S.y, T.y) - om;
    float m2 = fmaf(2.f, S.z, T.z) - om;
    float m3 = fmaf(2.f, S.w, T.w) - om;
    if (lane >= 25) { m0 = 0.f; m1 = 0.f; m2 = 0.f; m3 = 0.f; }
    float ss = (m0 + m1) + (m2 + m3);
    #pragma unroll
    for (int msk = 1; msk < 32; msk <<= 1) ss += __shfl_xor(ss, msk, 32);
    float rn = 1.f / (ss + om);
    float* orow = &out[(size_t)(R0 + srow) * 101];
    if (lane < 25) {
      orow[lane * 4 + 0] = m0 * rn; orow[lane * 4 + 1] = m1 * rn;
      orow[lane * 4 + 2] = m2 * rn; orow[lane * 4 + 3] = m3 * rn;
    } else if (lane == 25) {
      orow[100] = om * rn;
    }
  }
}

extern "C" void kernel_launch(void* const* d_in, const int* in_sizes, int n_in,
                              void* d_out, int out_size, void* d_ws, size_t ws_size,
                              hipStream_t stream)
{
  const float* x    = (const float*)d_in[0];
  const float* w    = (const float*)d_in[1];
  const float* xi   = (const float*)d_in[2];
  const float* eta  = (const float*)d_in[3];
  const float* beta = (const float*)d_in[4];
  (void)d_ws; (void)ws_size;
  hipLaunchKernelGGL(ds_one, dim3(NB / NR), dim3(256), 0, stream,
                     x, w, xi, eta, beta, (float*)d_out);
}

// Round 11
// 84.495 us; speedup vs baseline: 1.2030x; 1.0006x over previous
//
#include <hip/hip_runtime.h>
#include <math.h>

#define NB 8192
#define NF 512
#define NP 64
#define NC 100
#define NR 16
#define EPSF 1e-4f
#define LOG2E  1.44269504088896340736f

using short8  = __attribute__((ext_vector_type(8))) short;
using floatx4 = __attribute__((ext_vector_type(4))) float;

// pack 2 f32 -> bf16 pair in one dword (truncation); validated R6-R10
__device__ __forceinline__ unsigned pk2(float a, float b) {
  return (__float_as_uint(b) & 0xffff0000u) | (__float_as_uint(a) >> 16);
}
__device__ __forceinline__ uint2 pkbf(float4 v) {
  uint2 r; r.x = pk2(v.x, v.y); r.y = pk2(v.z, v.w); return r;
}
__device__ __forceinline__ float rlane(float v, int l) {
  return __uint_as_float(__builtin_amdgcn_readlane(__float_as_uint(v), l));
}

// ---- LDS layout (bytes) ----
// staging xh[16][136]s / wh[64][136]s [0,21760) unions u_l bf16[64][128] [0,16384)
#define OFF_XH    0
#define OFF_WH    4352
#define OFF_U     0
#define OFF_SI    21760
#define OFF_PK4   25856
#define OFF_REDB  29952
#define OFF_RMAX  30976
#define OFF_UMAX  31232
#define OFF_XSQL  31488
#define OFF_WSQL  31552
#define OFF_KGAM  31808
#define OFF_ALPH  32064
#define SMEM_SZ   32320

// One fused kernel, 512 blocks (2/CU) x 256 threads, 16 rows/block.
// GEMM (R8/R10-validated): bf16 MFMA 16x16x32, BK=128, register prefetch,
//   stride-136 staging (conflict-free b128 frag reads).
// Scan (suffix-product form, R7-validated; NEW row/lane mapping):
//   (T,S) over a contiguous p-segment compose associatively:
//   (T,S)_{A∪B} = (T_A·T_B, S_A·T_B + S_B)  [A = lower p's].
//   One WAVE per row: half-wave A handles p 0..31, B handles p 32..63
//   (each descending), 4 classes/lane; cross-half combine via shfl_xor 32.
//   u (bf16) preloaded ONCE per wave into 64 VGPRs, reused for all 4 rows;
//   per-iter LDS = 1 ds_read_b128 of (st,ot,W) [2-way addr = free].
//   pk4/omf wave-private: ds_write -> ds_read same wave, lgkmcnt-ordered
//   (barrier-free pattern validated R9/R10).
// All reductions butterflies/fixed-order => bitwise deterministic.
__global__ __launch_bounds__(256, 2)
void ds_one(const float* __restrict__ x, const float* __restrict__ w,
            const float* __restrict__ xi, const float* __restrict__ eta,
            const float* __restrict__ beta, float* __restrict__ out)
{
  __shared__ __align__(16) char smem[SMEM_SZ];
  short*          xh    = (short*)(smem + OFF_XH);
  short*          wh    = (short*)(smem + OFF_WH);
  unsigned short* u_l   = (unsigned short*)(smem + OFF_U);
  float*          si_l  = (float*)(smem + OFF_SI);
  float4*         pk4   = (float4*)(smem + OFF_PK4);
  float*          redb  = (float*)(smem + OFF_REDB);
  float*          rmax  = (float*)(smem + OFF_RMAX);
  float*          umaxl = (float*)(smem + OFF_UMAX);
  float*          xsql  = (float*)(smem + OFF_XSQL);
  float*          wsql  = (float*)(smem + OFF_WSQL);
  float*          kgaml = (float*)(smem + OFF_KGAM);
  float*          alphl = (float*)(smem + OFF_ALPH);

  const int t    = threadIdx.x;
  const int R0   = blockIdx.x * NR;
  const int wv   = t >> 6;
  const int wl   = t & 63;
  const int ml   = wl & 15;               // MFMA m/n lane
  const int qd   = wl >> 4;               // MFMA quad
  const int pcol = wv * 16 + ml;
  const int xrow = t >> 4, xq = t & 15;   // staging roles

  // ---- GEMM: D = x . w^T, BK=128, 4 chunks, register prefetch ----
  float xsq_acc = 0.f;
  float wacc[4] = {0.f, 0.f, 0.f, 0.f};
  floatx4 acc = {0.f, 0.f, 0.f, 0.f};
  float4 xr0, xr1, wr[4][2];

  {   // prefetch chunk 0
    const float* xp = &x[(size_t)(R0 + xrow) * NF + xq * 8];
    xr0 = *(const float4*)&xp[0];  xr1 = *(const float4*)&xp[4];
    #pragma unroll
    for (int g = 0; g < 4; ++g) {
      const int row = wv * 16 + g * 4 + (wl >> 4);
      const float* wp = &w[(size_t)row * NF + xq * 8];
      wr[g][0] = *(const float4*)&wp[0];  wr[g][1] = *(const float4*)&wp[4];
    }
  }
  for (int ch = 0; ch < 4; ++ch) {
    __syncthreads();                      // prev chunk's frags consumed
    {
      xsq_acc += xr0.x*xr0.x + xr0.y*xr0.y + xr0.z*xr0.z + xr0.w*xr0.w
               + xr1.x*xr1.x + xr1.y*xr1.y + xr1.z*xr1.z + xr1.w*xr1.w;
      *(uint2*)&xh[xrow * 136 + xq * 8]     = pkbf(xr0);
      *(uint2*)&xh[xrow * 136 + xq * 8 + 4] = pkbf(xr1);
    }
    #pragma unroll
    for (int g = 0; g < 4; ++g) {
      const int row = wv * 16 + g * 4 + (wl >> 4);
      float4 a = wr[g][0], b = wr[g][1];
      wacc[g] += a.x*a.x + a.y*a.y + a.z*a.z + a.w*a.w
               + b.x*b.x + b.y*b.y + b.z*b.z + b.w*b.w;
      *(uint2*)&wh[row * 136 + xq * 8]     = pkbf(a);
      *(uint2*)&wh[row * 136 + xq * 8 + 4] = pkbf(b);
    }
    __syncthreads();
    if (ch < 3) {                         // prefetch next chunk (overlaps MFMA)
      const int kb = (ch + 1) * 128;
      const float* xp = &x[(size_t)(R0 + xrow) * NF + kb + xq * 8];
      xr0 = *(const float4*)&xp[0];  xr1 = *(const float4*)&xp[4];
      #pragma unroll
      for (int g = 0; g < 4; ++g) {
        const int row = wv * 16 + g * 4 + (wl >> 4);
        const float* wp = &w[(size_t)row * NF + kb + xq * 8];
        wr[g][0] = *(const float4*)&wp[0];  wr[g][1] = *(const float4*)&wp[4];
      }
    }
    #pragma unroll
    for (int ks = 0; ks < 4; ++ks) {
      short8 a = *(const short8*)&xh[ml * 136 + ks * 32 + qd * 8];
      short8 b = *(const short8*)&wh[(wv * 16 + ml) * 136 + ks * 32 + qd * 8];
      acc = __builtin_amdgcn_mfma_f32_16x16x32_bf16(a, b, acc, 0, 0, 0);
    }
  }

  // ---- P1: beta partials; xsq/wsq butterflies; kgam/alpha ----
  const int p4 = t >> 2, q4 = t & 3;
  {
    const float* br = beta + p4 * NC + q4 * 25;
    float s = 0.f;
    #pragma unroll 5
    for (int j = 0; j < 25; ++j) { float b = br[j]; s = fmaf(b, b, s); }
    redb[q4 * 64 + p4] = s;
  }
  {
    float s = xsq_acc;
    s += __shfl_xor(s, 1, 64); s += __shfl_xor(s, 2, 64);
    s += __shfl_xor(s, 4, 64); s += __shfl_xor(s, 8, 64);
    if (xq == 0) xsql[xrow] = s;
  }
  #pragma unroll
  for (int g = 0; g < 4; ++g) {
    float s = wacc[g];
    s += __shfl_xor(s, 1, 64); s += __shfl_xor(s, 2, 64);
    s += __shfl_xor(s, 4, 64); s += __shfl_xor(s, 8, 64);
    if (xq == 0) wsql[wv * 16 + g * 4 + (wl >> 4)] = s;
  }
  if (t < 64) {
    float e = eta[t];
    kgaml[t] = -LOG2E * e * e;            // exp(-g*d) = exp2(kgam*d)
    alphl[t] = 1.f / (1.f + __expf(-xi[t]));
  }
  __syncthreads();                        // B1

  // ---- P2: si in MFMA-C layout + per-row 16-lane max partials ----
  float si4[4];
  {
    const float wq = wsql[pcol], kg = kgaml[pcol], al = alphl[pcol];
    #pragma unroll
    for (int i = 0; i < 4; ++i) {
      float d = xsql[qd * 4 + i] + wq - 2.f * acc[i];
      si4[i] = al * exp2f(kg * d);
    }
    #pragma unroll
    for (int i = 0; i < 4; ++i) {
      float m = si4[i];
      m = fmaxf(m, __shfl_xor(m, 1, 64)); m = fmaxf(m, __shfl_xor(m, 2, 64));
      m = fmaxf(m, __shfl_xor(m, 4, 64)); m = fmaxf(m, __shfl_xor(m, 8, 64));
      if (ml == 0) rmax[(qd * 4 + i) * 4 + wv] = m;
    }
  }
  __syncthreads();                        // B2

  // ---- P3: si finalize -> si_l; u fill (bf16, over dead staging) + umax ----
  #pragma unroll
  for (int i = 0; i < 4; ++i) {
    const int row = qd * 4 + i;
    float m = fmaxf(fmaxf(rmax[row * 4 + 0], rmax[row * 4 + 1]),
                    fmaxf(rmax[row * 4 + 2], rmax[row * 4 + 3]));
    si_l[row * 64 + pcol] = si4[i] * (1.f / (m + EPSF));
  }
  {
    const float bi = 1.f / (((redb[p4] + redb[64 + p4]) + redb[128 + p4]) + redb[192 + p4]);
    float um = 0.f;
    #pragma unroll
    for (int i2 = 0; i2 < 8; ++i2) {
      const int q = q4 + 4 * i2;          // col quad 0..31 (NC=100 = quads 0..24)
      float4 uv = make_float4(0.f, 0.f, 0.f, 0.f);
      if (q < 25) {
        const float* br = beta + p4 * NC + q * 4;
        uv.x = br[0]*br[0]*bi; uv.y = br[1]*br[1]*bi;
        uv.z = br[2]*br[2]*bi; uv.w = br[3]*br[3]*bi;
      }
      um = fmaxf(um, fmaxf(fmaxf(uv.x, uv.y), fmaxf(uv.z, uv.w)));
      *(uint2*)&u_l[p4 * 128 + q * 4] = pkbf(uv);
    }
    um = fmaxf(um, __shfl_xor(um, 1, 64));
    um = fmaxf(um, __shfl_xor(um, 2, 64));
    if (q4 == 0) umaxl[p4] = um;
  }
  __syncthreads();                        // B3 (last barrier)

  // ---- scan: one WAVE per row (4 rows/wave); p split across half-waves ----
  const int l31   = wl & 31;
  const int cbase = l31 * 4;              // this lane's 4 classes
  const int pbase = (wl >> 5) * 32;       // half A: p 0..31, half B: 32..63
  const bool isA  = (wl < 32);

  // preload u (bf16) for my half's 32 p values, 4 classes/lane: 64 VGPRs
  uint2 ureg[32];
  #pragma unroll
  for (int i = 0; i < 32; ++i)
    ureg[i] = *(const uint2*)&u_l[(pbase + i) * 128 + cbase];

  #pragma unroll 1
  for (int r = 0; r < 4; ++r) {
    const int srow = wv * 4 + r;
    // factors (lane = p over full wave), Kogge-Stone on 3*omt folds 3^k
    float sp = si_l[srow * 64 + wl];
    float um = umaxl[wl];
    float om = 1.f - sp;
    float cn = 1.f / fmaf(sp, um, om);    // scale: max_c(vt) ~ 1 -> T <= 1
    float ST = sp * cn, OT = om * cn;
    float P3 = 3.f * OT;
    #pragma unroll
    for (int d2 = 1; d2 < 64; d2 <<= 1) {
      float up = __shfl_up(P3, d2, 64);
      if (wl >= d2) P3 *= up;
    }
    float W    = (wl == 0) ? 0.f : P3 * (1.f / 9.f);  // 3^(k-1) prod_{j<=k} omt
    float omfr = rlane(P3, 63) * (1.f / 3.f);         // 3^63 prod omt
    pk4[(wv << 6) + wl] = make_float4(ST, OT, W, 0.f);
    // wave-private pk4: ds_write -> ds_read ordered by lgkmcnt, no barrier

    float4 T = make_float4(1.f, 1.f, 1.f, 1.f);
    float4 S = make_float4(0.f, 0.f, 0.f, 0.f);
    #pragma unroll
    for (int i = 31; i >= 0; --i) {       // descending within my segment
      float4 f = pk4[(wv << 6) + pbase + i];   // (st, ot, W): 2-addr b128
      uint2 ud = ureg[i];
      float u0 = __uint_as_float(ud.x << 16);
      float u1 = __uint_as_float(ud.x & 0xffff0000u);
      float u2 = __uint_as_float(ud.y << 16);
      float u3 = __uint_as_float(ud.y & 0xffff0000u);
      S.x = fmaf(f.z, T.x, S.x); S.y = fmaf(f.z, T.y, S.y);
      S.z = fmaf(f.z, T.z, S.z); S.w = fmaf(f.z, T.w, S.w);
      T.x *= fmaf(f.x, u0, f.y);
      T.y *= fmaf(f.x, u1, f.y);
      T.z *= fmaf(f.x, u2, f.y);
      T.w *= fmaf(f.x, u3, f.y);
    }
    // combine halves: (T,S)_full = (T_A*T_B, S_A*T_B + S_B)
    float4 To, So;
    To.x = __shfl_xor(T.x, 32, 64); To.y = __shfl_xor(T.y, 32, 64);
    To.z = __shfl_xor(T.z, 32, 64); To.w = __shfl_xor(T.w, 32, 64);
    So.x = __shfl_xor(S.x, 32, 64); So.y = __shfl_xor(S.y, 32, 64);
    So.z = __shfl_xor(S.z, 32, 64); So.w = __shfl_xor(S.w, 32, 64);
    #define CMB(c) { \
      float SA = isA ? S.c : So.c; \
      float TB = isA ? To.c : T.c; \
      float SB = isA ? So.c : S.c; \
      S.c = fmaf(SA, TB, SB);  T.c = T.c * To.c; }
    CMB(x) CMB(y) CMB(z) CMB(w)
    #undef CMB

    float m0 = fmaf(2.f, S.x, T.x) - omfr;
    float m1 = fmaf(2.f, S.y, T.y) - omfr;
    float m2 = fmaf(2.f, S.z, T.z) - omfr;
    float m3 = fmaf(2.f, S.w, T.w) - omfr;
    if (l31 >= 25) { m0 = 0.f; m1 = 0.f; m2 = 0.f; m3 = 0.f; }
    float ss = (m0 + m1) + (m2 + m3);
    #pragma unroll
    for (int msk = 1; msk < 32; msk <<= 1) ss += __shfl_xor(ss, msk, 64);
    float rn = 1.f / (ss + omfr);
    float* orow = &out[(size_t)(R0 + srow) * 101];
    if (wl < 25) {
      orow[wl * 4 + 0] = m0 * rn; orow[wl * 4 + 1] = m1 * rn;
      orow[wl * 4 + 2] = m2 * rn; orow[wl * 4 + 3] = m3 * rn;
    } else if (wl == 25) {
      orow[100] = omfr * rn;
    }
  }
}

extern "C" void kernel_launch(void* const* d_in, const int* in_sizes, int n_in,
                              void* d_out, int out_size, void* d_ws, size_t ws_size,
                              hipStream_t stream)
{
  const float* x    = (const float*)d_in[0];
  const float* w    = (const float*)d_in[1];
  const float* xi   = (const float*)d_in[2];
  const float* eta  = (const float*)d_in[3];
  const float* beta = (const float*)d_in[4];
  (void)d_ws; (void)ws_size;
  hipLaunchKernelGGL(ds_one, dim3(NB / NR), dim3(256), 0, stream,
                     x, w, xi, eta, beta, (float*)d_out);
}